// Round 5
// baseline (792.660 us; speedup 1.0000x reference)
//
#include <hip/hip_runtime.h>
#include <cstdint>

typedef unsigned short u16;
typedef unsigned int   u32;
typedef __bf16 bf16x8 __attribute__((ext_vector_type(8)));
typedef float  f32x4  __attribute__((ext_vector_type(4)));

#define NCTX 10
#define BSZ  32
#define IDF  256
#define QSZ  1024
#define CDF  512
#define LSZ  128

__device__ __forceinline__ u16 f2bf(float f) {
    u32 u = __float_as_uint(f);
    u += 0x7FFFu + ((u >> 16) & 1u);          // RNE to bf16
    return (u16)(u >> 16);
}
__device__ __forceinline__ float bf2f(u16 h) {
    return __uint_as_float(((u32)h) << 16);
}

union U4V { uint4 u; bf16x8 v; };

__device__ __forceinline__ bf16x8 ldg16(const u16* p) {   // 8 contiguous bf16 (16B)
    U4V t; t.u = *(const uint4*)p; return t.v;
}
__device__ __forceinline__ bf16x8 lds16(const u16* p) {
    U4V t; t.u = *(const uint4*)p; return t.v;
}
__device__ __forceinline__ f32x4 mfma16(bf16x8 a, bf16x8 b, f32x4 c) {
    return __builtin_amdgcn_mfma_f32_16x16x32_bf16(a, b, c, 0, 0, 0);
}

// ---------------- K1a: weights -> bf16 (Wc hi/lo, Wcat plain) ----------------
__global__ __launch_bounds__(256) void k1a_conv(const float* __restrict__ Wc,
                                                const float* __restrict__ Wcat,
                                                u16* __restrict__ Wc_hi,
                                                u16* __restrict__ Wc_lo,
                                                u16* __restrict__ Wcat_bf) {
    int i = blockIdx.x * 256 + threadIdx.x;
    if (i < IDF * CDF) {
        float f = Wc[i];
        u16 h = f2bf(f);
        Wc_hi[i] = h;
        Wc_lo[i] = f2bf(f - bf2f(h));
    } else {
        int j = i - IDF * CDF;
        Wcat_bf[j] = f2bf(Wcat[j]);
    }
}

// ---------------- K1b: input [B,idf,Q] -> T_hi/T_lo [B,Q,idf] ----------------
__global__ __launch_bounds__(256) void k1b_tgt(const float* __restrict__ input,
                                               u16* __restrict__ T_hi,
                                               u16* __restrict__ T_lo) {
    __shared__ float t[32 * 132];
    const int tid = threadIdx.x;
    const int qt = blockIdx.x, dt = blockIdx.y, b = blockIdx.z;
#pragma unroll
    for (int k = 0; k < 4; ++k) {
        const int idx = tid + k * 256;
        const int d = idx >> 5, c4 = idx & 31;
        const float4 v = *(const float4*)(input +
            ((long)(b * IDF + dt * 32 + d)) * QSZ + qt * 128 + c4 * 4);
        *(float4*)(t + d * 132 + c4 * 4) = v;
    }
    __syncthreads();
#pragma unroll
    for (int k = 0; k < 2; ++k) {
        const int idx = tid + k * 256;
        const int q = idx >> 2, dg = idx & 3;
        u16 hi[8], lo[8];
#pragma unroll
        for (int jj = 0; jj < 8; ++jj) {
            float f = t[(dg * 8 + jj) * 132 + q];
            u16 h = f2bf(f);
            hi[jj] = h;
            lo[jj] = f2bf(f - bf2f(h));
        }
        const long o = ((long)(b * QSZ + qt * 128 + q)) * IDF + dt * 32 + dg * 8;
        *(uint4*)(T_hi + o) = *(const uint4*)hi;
        *(uint4*)(T_lo + o) = *(const uint4*)lo;
    }
}

// ---------------- K1c: contexts [n,b,c,l] -> ctxT bf16 [n,b,l,c] -------------
__global__ __launch_bounds__(256) void k1c_ctx(const float* __restrict__ ctx,
                                               u16* __restrict__ ctxT) {
    __shared__ float t[32 * 132];
    const int tid = threadIdx.x;
    const int ct = blockIdx.x, nb = blockIdx.y;
#pragma unroll
    for (int k = 0; k < 4; ++k) {
        const int idx = tid + k * 256;
        const int c = idx >> 5, l4 = idx & 31;
        const float4 v = *(const float4*)(ctx +
            ((long)(nb * CDF + ct * 32 + c)) * LSZ + l4 * 4);
        *(float4*)(t + c * 132 + l4 * 4) = v;
    }
    __syncthreads();
#pragma unroll
    for (int k = 0; k < 2; ++k) {
        const int idx = tid + k * 256;
        const int l = idx >> 2, dg = idx & 3;
        u16 bv[8];
#pragma unroll
        for (int jj = 0; jj < 8; ++jj)
            bv[jj] = f2bf(t[(dg * 8 + jj) * 132 + l]);
        *(uint4*)(ctxT + ((long)(nb * LSZ + l)) * CDF + ct * 32 + dg * 8) =
            *(const uint4*)bv;
    }
}

// ---------------- K2: sourceT = Wc @ ctx  (per (n,b), hi/lo x hi) ------------
// 2-stage register prefetch across the 16-kc K loop.
__global__ __launch_bounds__(256, 2) void k2_src(const u16* __restrict__ Wc_hi,
                                                 const u16* __restrict__ Wc_lo,
                                                 const u16* __restrict__ ctxT,
                                                 u16* __restrict__ sTT_hi,
                                                 u16* __restrict__ sTT_lo,
                                                 u16* __restrict__ s_dl) {
    __shared__ u16 bounce[128 * 136];
    const int tid = threadIdx.x;
    const int L = tid & 63, w = tid >> 6;
    const int wd = w >> 1, wl = w & 1, lr = L & 15, quad = L >> 4;
    const int dbase = blockIdx.x * 128;
    const int nb = blockIdx.y;
    const u16* ctxb = ctxT + (long)nb * LSZ * CDF;

    const f32x4 vz = {0.f, 0.f, 0.f, 0.f};
    f32x4 acc[4][4];
#pragma unroll
    for (int m = 0; m < 4; ++m)
#pragma unroll
        for (int nn = 0; nn < 4; ++nn) acc[m][nn] = vz;

    bf16x8 aH[2][4], aL[2][4], bb[2][4];
    auto loadK2 = [&](int kc, int s) {
        const int c0 = kc * 32 + quad * 8;
#pragma unroll
        for (int m = 0; m < 4; ++m) {
            const int d = dbase + 64 * wd + 16 * m + lr;
            aH[s][m] = ldg16(Wc_hi + d * CDF + c0);
            aL[s][m] = ldg16(Wc_lo + d * CDF + c0);
        }
#pragma unroll
        for (int nn = 0; nn < 4; ++nn) {
            const int l = 64 * wl + 16 * nn + lr;
            bb[s][nn] = ldg16(ctxb + l * CDF + c0);
        }
    };

    loadK2(0, 0);
#pragma unroll
    for (int kc = 0; kc < 16; ++kc) {
        const int cur = kc & 1;
        if (kc < 15) loadK2(kc + 1, cur ^ 1);
#pragma unroll
        for (int m = 0; m < 4; ++m)
#pragma unroll
            for (int nn = 0; nn < 4; ++nn) {
                acc[m][nn] = mfma16(aH[cur][m], bb[cur][nn], acc[m][nn]);
                acc[m][nn] = mfma16(aL[cur][m], bb[cur][nn], acc[m][nn]);
            }
    }

    // pass 1: hi, transposed [l][d]
#pragma unroll
    for (int m = 0; m < 4; ++m)
#pragma unroll
        for (int nn = 0; nn < 4; ++nn)
#pragma unroll
            for (int r = 0; r < 4; ++r) {
                const int d = 64 * wd + 16 * m + 4 * quad + r;
                const int l = 64 * wl + 16 * nn + lr;
                bounce[l * 136 + d] = f2bf(acc[m][nn][r]);
            }
    __syncthreads();
    for (int i = tid; i < 2048; i += 256) {
        const int l = i >> 4, g = (i & 15) * 8;
        *(uint4*)(sTT_hi + ((long)nb * LSZ + l) * IDF + dbase + g) =
            *(const uint4*)(bounce + l * 136 + g);
    }
    __syncthreads();
    // pass 2: lo, transposed [l][d]
#pragma unroll
    for (int m = 0; m < 4; ++m)
#pragma unroll
        for (int nn = 0; nn < 4; ++nn)
#pragma unroll
            for (int r = 0; r < 4; ++r) {
                const int d = 64 * wd + 16 * m + 4 * quad + r;
                const int l = 64 * wl + 16 * nn + lr;
                float c = acc[m][nn][r];
                u16 h = f2bf(c);
                bounce[l * 136 + d] = f2bf(c - bf2f(h));
            }
    __syncthreads();
    for (int i = tid; i < 2048; i += 256) {
        const int l = i >> 4, g = (i & 15) * 8;
        *(uint4*)(sTT_lo + ((long)nb * LSZ + l) * IDF + dbase + g) =
            *(const uint4*)(bounce + l * 136 + g);
    }
    __syncthreads();
    // pass 3: hi, natural [d][l]
#pragma unroll
    for (int m = 0; m < 4; ++m)
#pragma unroll
        for (int nn = 0; nn < 4; ++nn)
#pragma unroll
            for (int r = 0; r < 4; ++r) {
                const int d = 64 * wd + 16 * m + 4 * quad + r;
                const int l = 64 * wl + 16 * nn + lr;
                bounce[d * 136 + l] = f2bf(acc[m][nn][r]);
            }
    __syncthreads();
    for (int i = tid; i < 2048; i += 256) {
        const int d = i >> 4, g = (i & 15) * 8;
        *(uint4*)(s_dl + ((long)nb * IDF + dbase + d) * LSZ + g) =
            *(const uint4*)(bounce + d * 136 + g);
    }
}

// ---------------- K3: fused scores->softmax->PV->concat-proj->LN -------------
// 128-row q tiles, 512 threads (8 waves), grid 256 = 1 block/CU.
// Explicit 2-stage register prefetch within phases + cross-barrier global
// prefetch (all global operands are barrier-independent; only E/attnL LDS
// reads need the 2 barriers per n).
__global__ __launch_bounds__(512, 2) void k3_attn(
    const u16* __restrict__ T_hi, const u16* __restrict__ T_lo,
    const u16* __restrict__ sTT_hi, const u16* __restrict__ sTT_lo,
    const u16* __restrict__ s_dl, const u16* __restrict__ Wcat_bf,
    const float* __restrict__ Wb, const float* __restrict__ gam_p,
    const float* __restrict__ bet_p, float* __restrict__ out)
{
    __shared__ __align__(16) u16 E[128 * 136];      // exp(S), unnormalized (34.8 KB)
    __shared__ __align__(16) u16 attnL[128 * 264];  // normalized attn (67.6 KB)
    __shared__ float red[128 * 2];
    __shared__ float red2[128 * 4];

    const int tid = threadIdx.x;
    const int L = tid & 63, w = tid >> 6;
    const int lr = L & 15, quad = L >> 4;
    const int wq = w & 3, wl = w >> 2;
    const int i = blockIdx.x;
    const int b = (i & 7) * 4 + ((i >> 3) & 3);
    const int qt = i >> 5;                          // 0..7
    const int bq = b * QSZ + qt * 128;

    const f32x4 vz = {0.f, 0.f, 0.f, 0.f};
    f32x4 x_acc[2][8];
#pragma unroll
    for (int m = 0; m < 2; ++m)
#pragma unroll
        for (int nn = 0; nn < 8; ++nn) x_acc[m][nn] = vz;

    // ---- pipeline register buffers ----
    bf16x8 aH[2][2], aL[2][2], bH[2][4], bL[2][4];  // phase-1 frags (96 VGPR)
    bf16x8 gB[2][8];                                // phase-2/3 B frags (64 VGPR)

    const long arow0 = (long)(bq + 32 * wq + lr) * IDF;   // T row, m=0
    const long arow1 = arow0 + 16 * IDF;                  // T row, m=1
    const long brow0 = (long)(64 * wl + lr) * IDF;        // sTT row base (in-slice)

    auto loadP1 = [&](const u16* sh, const u16* sl, int kc, int s) {
        const int c0 = kc * 32 + quad * 8;
        aH[s][0] = ldg16(T_hi + arow0 + c0);
        aL[s][0] = ldg16(T_lo + arow0 + c0);
        aH[s][1] = ldg16(T_hi + arow1 + c0);
        aL[s][1] = ldg16(T_lo + arow1 + c0);
#pragma unroll
        for (int nn = 0; nn < 4; ++nn) {
            const long ro = brow0 + (long)(16 * nn) * IDF + c0;
            bH[s][nn] = ldg16(sh + ro);
            bL[s][nn] = ldg16(sl + ro);
        }
    };
    auto loadSdl = [&](const u16* sdl, int kc, int s) {
        const int l0 = kc * 32 + quad * 8;
#pragma unroll
        for (int nn = 0; nn < 8; ++nn)
            gB[s][nn] = ldg16(sdl + (long)(128 * wl + 16 * nn + lr) * LSZ + l0);
    };
    auto loadWcat = [&](const u16* wcat, int kc, int s) {
        const int d0 = kc * 32 + quad * 8;
#pragma unroll
        for (int nn = 0; nn < 8; ++nn)
            gB[s][nn] = ldg16(wcat + (long)(128 * wl + 16 * nn + lr) * (NCTX * IDF) + d0);
    };

    // prologue: phase-1 kc=0 of n=0
    loadP1(sTT_hi + (long)b * (LSZ * IDF), sTT_lo + (long)b * (LSZ * IDF), 0, 0);

    for (int n = 0; n < NCTX; ++n) {
        const int nb = n * BSZ + b;
        const u16* sttH = sTT_hi + (long)nb * (LSZ * IDF);
        const u16* sttL = sTT_lo + (long)nb * (LSZ * IDF);
        const u16* sdl  = s_dl  + (long)nb * (IDF * LSZ);
        const u16* wcat = Wcat_bf + n * IDF;

        // ---- phase 1: S[128q x 128l] (2-stage prefetch; kc=0 already loaded)
        f32x4 s_acc[2][4];
#pragma unroll
        for (int m = 0; m < 2; ++m)
#pragma unroll
            for (int nn = 0; nn < 4; ++nn) s_acc[m][nn] = vz;

#pragma unroll
        for (int kc = 0; kc < 8; ++kc) {
            const int cur = kc & 1;
            if (kc < 7) loadP1(sttH, sttL, kc + 1, cur ^ 1);
            else        loadSdl(sdl, 0, 0);       // bridge into phase 2
#pragma unroll
            for (int m = 0; m < 2; ++m)
#pragma unroll
                for (int nn = 0; nn < 4; ++nn) {
                    s_acc[m][nn] = mfma16(aH[cur][m], bH[cur][nn], s_acc[m][nn]);
                    s_acc[m][nn] = mfma16(aH[cur][m], bL[cur][nn], s_acc[m][nn]);
                    s_acc[m][nn] = mfma16(aL[cur][m], bH[cur][nn], s_acc[m][nn]);
                }
        }

        // ---- softmax in registers (no max-sub; |S| << 88 overflow limit)
        float rs_[2][4];
#pragma unroll
        for (int m = 0; m < 2; ++m)
#pragma unroll
            for (int r = 0; r < 4; ++r) rs_[m][r] = 0.f;
#pragma unroll
        for (int m = 0; m < 2; ++m)
#pragma unroll
            for (int nn = 0; nn < 4; ++nn)
#pragma unroll
                for (int r = 0; r < 4; ++r) {
                    const float e = __expf(s_acc[m][nn][r]);
                    rs_[m][r] += e;
                    E[(32 * wq + 16 * m + 4 * quad + r) * 136 + 64 * wl + 16 * nn + lr]
                        = f2bf(e);
                }
#pragma unroll
        for (int off = 1; off <= 8; off <<= 1)
#pragma unroll
            for (int m = 0; m < 2; ++m)
#pragma unroll
                for (int r = 0; r < 4; ++r)
                    rs_[m][r] += __shfl_xor(rs_[m][r], off);
        if (lr == 0) {
#pragma unroll
            for (int m = 0; m < 2; ++m)
#pragma unroll
                for (int r = 0; r < 4; ++r)
                    red[(32 * wq + 16 * m + 4 * quad + r) * 2 + wl] = rs_[m][r];
        }
        __syncthreads();                            // B1: E + row partial sums ready

        float invr[2][4];
#pragma unroll
        for (int m = 0; m < 2; ++m)
#pragma unroll
            for (int r = 0; r < 4; ++r) {
                const int row = 32 * wq + 16 * m + 4 * quad + r;
                invr[m][r] = 1.0f / (red[row * 2] + red[row * 2 + 1]);
            }

        // ---- phase 2: attn[128q x 256d] (gB[0] holds s_dl kc=0)
        f32x4 a_acc[2][8];
#pragma unroll
        for (int m = 0; m < 2; ++m)
#pragma unroll
            for (int nn = 0; nn < 8; ++nn) a_acc[m][nn] = vz;

#pragma unroll
        for (int kc = 0; kc < 4; ++kc) {
            const int cur = kc & 1;
            if (kc < 3) loadSdl(sdl, kc + 1, cur ^ 1);
            else        loadWcat(wcat, 0, cur ^ 1); // kc=3: nxt=0 -> phase-3 kc=0
            const int l0 = kc * 32 + quad * 8;
            const bf16x8 af0 = lds16(E + (32 * wq + lr) * 136 + l0);
            const bf16x8 af1 = lds16(E + (32 * wq + 16 + lr) * 136 + l0);
#pragma unroll
            for (int nn = 0; nn < 8; ++nn) {
                a_acc[0][nn] = mfma16(af0, gB[cur][nn], a_acc[0][nn]);
                a_acc[1][nn] = mfma16(af1, gB[cur][nn], a_acc[1][nn]);
            }
        }
#pragma unroll
        for (int m = 0; m < 2; ++m)
#pragma unroll
            for (int nn = 0; nn < 8; ++nn)
#pragma unroll
                for (int r = 0; r < 4; ++r)
                    attnL[(32 * wq + 16 * m + 4 * quad + r) * 264 + 128 * wl + 16 * nn + lr]
                        = f2bf(a_acc[m][nn][r] * invr[m][r]);
        __syncthreads();                            // B2: attn ready

        // ---- phase 3: X += attn . Wcat_n^T (gB[0] holds wcat kc=0)
#pragma unroll
        for (int kc = 0; kc < 8; ++kc) {
            const int cur = kc & 1;
            if (kc < 7) loadWcat(wcat, kc + 1, cur ^ 1);
            else if (n < NCTX - 1)                  // bridge into next n's phase 1
                loadP1(sttH + (long)BSZ * LSZ * IDF, sttL + (long)BSZ * LSZ * IDF, 0, 0);
            const int d0 = kc * 32 + quad * 8;
            const bf16x8 af0 = lds16(attnL + (32 * wq + lr) * 264 + d0);
            const bf16x8 af1 = lds16(attnL + (32 * wq + 16 + lr) * 264 + d0);
#pragma unroll
            for (int nn = 0; nn < 8; ++nn) {
                x_acc[0][nn] = mfma16(af0, gB[cur][nn], x_acc[0][nn]);
                x_acc[1][nn] = mfma16(af1, gB[cur][nn], x_acc[1][nn]);
            }
        }
    }

    // ---- epilogue: bias + relu + residual + LayerNorm(eps=0) ----
    float gv[8], bv[8], wv[8];
    int ec[8];
#pragma unroll
    for (int nn = 0; nn < 8; ++nn) {
        ec[nn] = 128 * wl + 16 * nn + lr;
        wv[nn] = Wb[ec[nn]];
        gv[nn] = gam_p[ec[nn]];
        bv[nn] = bet_p[ec[nn]];
    }
    float s1[2][4], s2[2][4];
#pragma unroll
    for (int m = 0; m < 2; ++m)
#pragma unroll
        for (int r = 0; r < 4; ++r) {
            const int row = 32 * wq + 16 * m + 4 * quad + r;
            const u16* th = T_hi + (long)(bq + row) * IDF;
            const u16* tl = T_lo + (long)(bq + row) * IDF;
            float a = 0.f, q2 = 0.f;
#pragma unroll
            for (int nn = 0; nn < 8; ++nn) {
                const float resid = bf2f(th[ec[nn]]) + bf2f(tl[ec[nn]]);
                const float v = fmaxf(x_acc[m][nn][r] + wv[nn], 0.f) + resid;
                x_acc[m][nn][r] = v;
                a += v;
                q2 += v * v;
            }
            s1[m][r] = a;
            s2[m][r] = q2;
        }
#pragma unroll
    for (int off = 1; off <= 8; off <<= 1)
#pragma unroll
        for (int m = 0; m < 2; ++m)
#pragma unroll
            for (int r = 0; r < 4; ++r) {
                s1[m][r] += __shfl_xor(s1[m][r], off);
                s2[m][r] += __shfl_xor(s2[m][r], off);
            }
    if (lr == 0) {
#pragma unroll
        for (int m = 0; m < 2; ++m)
#pragma unroll
            for (int r = 0; r < 4; ++r) {
                const int row = 32 * wq + 16 * m + 4 * quad + r;
                red2[row * 4 + wl * 2]     = s1[m][r];
                red2[row * 4 + wl * 2 + 1] = s2[m][r];
            }
    }
    __syncthreads();
#pragma unroll
    for (int m = 0; m < 2; ++m)
#pragma unroll
        for (int r = 0; r < 4; ++r) {
            const int row = 32 * wq + 16 * m + 4 * quad + r;
            const float S1 = red2[row * 4] + red2[row * 4 + 2];
            const float S2 = red2[row * 4 + 1] + red2[row * 4 + 3];
            const float mu = S1 * (1.f / 256.f);
            const float rs = rsqrtf(S2 * (1.f / 256.f) - mu * mu);
            float* op = out + (long)(bq + row) * IDF;
#pragma unroll
            for (int nn = 0; nn < 8; ++nn)
                op[ec[nn]] = (x_acc[m][nn][r] - mu) * rs * gv[nn] + bv[nn];
        }
}

// ---------------- launch ----------------
extern "C" void kernel_launch(void* const* d_in, const int* in_sizes, int n_in,
                              void* d_out, int out_size, void* d_ws, size_t ws_size,
                              hipStream_t stream) {
    const float* input    = (const float*)d_in[0];
    const float* contexts = (const float*)d_in[1];
    const float* Wc       = (const float*)d_in[2];
    const float* Wcat     = (const float*)d_in[3];
    const float* Wb       = (const float*)d_in[4];
    const float* gamma    = (const float*)d_in[5];
    const float* beta     = (const float*)d_in[6];
    float* out = (float*)d_out;

    char* ws = (char*)d_ws;
    size_t off = 0;
    u16* Wc_hi   = (u16*)(ws + off); off += (size_t)IDF * CDF * 2;
    u16* Wc_lo   = (u16*)(ws + off); off += (size_t)IDF * CDF * 2;
    u16* Wcat_bf = (u16*)(ws + off); off += (size_t)IDF * NCTX * IDF * 2;
    u16* T_hi    = (u16*)(ws + off); off += (size_t)BSZ * QSZ * IDF * 2;
    u16* T_lo    = (u16*)(ws + off); off += (size_t)BSZ * QSZ * IDF * 2;
    u16* ctxT    = (u16*)(ws + off); off += (size_t)NCTX * BSZ * LSZ * CDF * 2;
    u16* sTT_hi  = (u16*)(ws + off); off += (size_t)NCTX * BSZ * LSZ * IDF * 2;
    u16* sTT_lo  = (u16*)(ws + off); off += (size_t)NCTX * BSZ * LSZ * IDF * 2;
    u16* s_dl    = (u16*)(ws + off); off += (size_t)NCTX * BSZ * IDF * LSZ * 2;
    (void)in_sizes; (void)n_in; (void)out_size; (void)ws_size;

    k1a_conv<<<3072, 256, 0, stream>>>(Wc, Wcat, Wc_hi, Wc_lo, Wcat_bf);
    k1b_tgt<<<dim3(QSZ / 128, IDF / 32, BSZ), 256, 0, stream>>>(input, T_hi, T_lo);
    k1c_ctx<<<dim3(CDF / 32, NCTX * BSZ), 256, 0, stream>>>(contexts, ctxT);
    k2_src<<<dim3(2, NCTX * BSZ), 256, 0, stream>>>(Wc_hi, Wc_lo, ctxT, sTT_hi, sTT_lo, s_dl);
    k3_attn<<<dim3(256), 512, 0, stream>>>(T_hi, T_lo, sTT_hi, sTT_lo, s_dl,
                                           Wcat_bf, Wb, gamma, beta, out);
}